// Round 11
// baseline (1212.499 us; speedup 1.0000x reference)
//
#include <hip/hip_runtime.h>

// ---------------------------------------------------------------------------
// TransformerAgent (Performer/FAVOR+ encoder), MI355X gfx950.
// Round 25: r24 + A-OPERAND DIRECT FROM GLOBAL in gemm_mfma.
// Pipe-level arithmetic: per block 512 ds_read_b128 (512KB) ~6200cyc + LDS
// writes ~4000cyc >> MFMA ~2500cyc -> LDS pipe co-dominant with HBM, never
// attacked across 10 structural variants (all kept 16 ds_read : 32 MFMA).
// Fix: a-frags read straight from global (16 rows x 64B contiguous per
// instr, L1/L2-served; A panel L2-resident via XCD swizzle). Removes half
// the ds_reads + 1/3 of LDS writes; LDS 48->32KB -> 4 blocks/CU (2x TLP).
// B staging/swizzle/math byte-identical. zero_kv fold + prep_all kept.
// Falsifier: FF1 >= 52us -> revert, declare practical plateau.
// B=16, L=4096(=1+4095), HID=256, NH=8, DH=32, FF=1024, NL=4, ACT=32
// ---------------------------------------------------------------------------

typedef unsigned short bf16_t;
typedef __attribute__((ext_vector_type(8))) short short8;
typedef __attribute__((ext_vector_type(4))) float float4v;

#define NB 16
#define LSEQ 4096
#define MROWS (NB * LSEQ)      // 65536
#define HIDD 256
#define NHEAD 8
#define DHEAD 32
#define FFD 1024
#define NLAY 4
#define KEPS_F 1e-3f
#define LNEPS_F 1e-6f
#define KV_ELEMS (NB * NHEAD * 32 * 33)   // 135168

__device__ __forceinline__ float b2f(bf16_t h) {
    return __uint_as_float(((unsigned int)h) << 16);
}
__device__ __forceinline__ bf16_t f2b(float f) {
    unsigned int u = __float_as_uint(f);
    u += 0x7fffu + ((u >> 16) & 1u);   // round-to-nearest-even
    return (bf16_t)(u >> 16);
}

// async global->LDS, 16B per lane
#define GLOAD_LDS16(g, l)                                                     \
    __builtin_amdgcn_global_load_lds(                                         \
        (const __attribute__((address_space(1))) void*)(g),                   \
        (__attribute__((address_space(3))) void*)(l), 16, 0, 0)

// raw barrier + counted waits (used by the pipe2_ln core)
#define SBAR() __builtin_amdgcn_s_barrier()
#define WAITV(n)                                                              \
    do {                                                                      \
        asm volatile("s_waitcnt vmcnt(" #n ")" ::: "memory");                 \
        __builtin_amdgcn_sched_barrier(0);                                    \
    } while (0)

// pipe2_ln fragment read: (row R, k-chunk quad) of a [256]x32 panel in
// pair-row-XOR-swizzled chunk order.
#define FRAG16(L, R)                                                          \
    (*(const short8*)&(L)[((((R) >> 1) * 8) +                                  \
        (((((R) & 1) << 2) | quad) ^ (((R) >> 1) & 7))) * 8])

// ---------------------------------------------------------------------------
// prep_all: ALL weight transposes + bias concat in ONE dispatch.
// Flat decode over 3108 blocks (tile math byte-identical to the proven
// conv_transpose_kernel).
// ---------------------------------------------------------------------------
__global__ __launch_bounds__(256) void prep_all(
    const float* __restrict__ Wq, const float* __restrict__ Wk,
    const float* __restrict__ Wv, const float* __restrict__ Wo,
    const float* __restrict__ W1, const float* __restrict__ W2,
    const float* __restrict__ embW,
    const float* __restrict__ bq, const float* __restrict__ bk,
    const float* __restrict__ bv,
    bf16_t* __restrict__ WqkvT, bf16_t* __restrict__ WoT,
    bf16_t* __restrict__ W1T, bf16_t* __restrict__ W2T,
    bf16_t* __restrict__ embWT, float* __restrict__ bqkv)
{
    const int id = blockIdx.x;
    if (id >= 3104) {                          // concat_bias: 4 blocks
        const int l = id - 3104, j = threadIdx.x;
        bqkv[l * 768 + j]       = bq[l * 256 + j];
        bqkv[l * 768 + 256 + j] = bk[l * 256 + j];
        bqkv[l * 768 + 512 + j] = bv[l * 256 + j];
        return;
    }
    const float* in; bf16_t* out;
    int R, C, z, x, y; size_t ils, ols;
    if (id < 1024) {
        const int seg = id >> 8;               // 0..3: Wq,Wk,Wv,Wo
        const int t = id & 255;
        z = t >> 6; const int tt = t & 63; x = tt & 7; y = tt >> 3;
        R = 256; C = 256; ils = 65536;
        if (seg == 0)      { in = Wq; out = WqkvT;              ols = 3 * 65536; }
        else if (seg == 1) { in = Wk; out = WqkvT + 65536;      ols = 3 * 65536; }
        else if (seg == 2) { in = Wv; out = WqkvT + 2 * 65536;  ols = 3 * 65536; }
        else               { in = Wo; out = WoT;                ols = 65536;     }
    } else if (id < 2048) {
        const int t2 = id - 1024; z = t2 >> 8; const int t = t2 & 255;
        x = t & 31; y = t >> 5; R = 256; C = 1024; ils = ols = 262144;
        in = W1; out = W1T;
    } else if (id < 3072) {
        const int t2 = id - 2048; z = t2 >> 8; const int t = t2 & 255;
        x = t & 7; y = t >> 3; R = 1024; C = 256; ils = ols = 262144;
        in = W2; out = W2T;
    } else {
        const int t = id - 3072; z = 0; x = t & 7; y = t >> 3;
        R = 128; C = 256; ils = 0; ols = 0;
        in = embW; out = embWT;
    }
    __shared__ float tile[32][33];
    const size_t ib = (size_t)z * ils;
    const size_t ob = (size_t)z * ols;
    const int r0 = y * 32, c0 = x * 32;
    const int tx = threadIdx.x & 31, ty = threadIdx.x >> 5;   // 32 x 8
#pragma unroll
    for (int rr = ty; rr < 32; rr += 8)
        tile[rr][tx] = in[ib + (size_t)(r0 + rr) * C + c0 + tx];
    __syncthreads();
#pragma unroll
    for (int rr = ty; rr < 32; rr += 8)
        out[ob + (size_t)(c0 + rr) * R + r0 + tx] = f2b(tile[tx][rr]);
}

// ---------------------------------------------------------------------------
// Embed A-prep: Ain[b*4096+l][128] = (l==0) ? 0 : bf16(ins[b][l-1][:])
// ---------------------------------------------------------------------------
__global__ __launch_bounds__(256) void prep_a_kernel(
    const float* __restrict__ ins, bf16_t* __restrict__ Ain)
{
    const int row = blockIdx.x * 2 + (threadIdx.x >> 7);
    const int j = threadIdx.x & 127;
    const int b = row >> 12, l = row & (LSEQ - 1);
    bf16_t v = 0;
    if (l != 0) v = f2b(ins[((size_t)b * 4095 + (l - 1)) * 128 + j]);
    Ain[(size_t)row * 128 + j] = v;
}

// X[b,0,:] = resets ? 0 : hidden
__global__ __launch_bounds__(256) void fix_row0_kernel(
    const float* __restrict__ hidden, const int* __restrict__ resets,
    bf16_t* __restrict__ X)
{
    const int b = blockIdx.x, j = threadIdx.x;
    float v = resets[b] ? 0.f : hidden[b * HIDD + j];
    X[((size_t)b * LSEQ) * HIDD + j] = f2b(v);
}

// ---------------------------------------------------------------------------
// MFMA GEMM, A-direct-from-global variant: C = act(A @ W + bias); WT[N][K].
// 512 thr = 8 waves, block 128x256, wave 64x64 (2m x 4n).
// A-fragments read straight from global (16 rows x 64B contiguous per
// instruction, L1/L2-served); B staged via gload_lds + XOR swizzle as before.
// LDS = 32 KB -> up to 4 blocks/CU. Optional side-task: zero zbuf at entry.
// 1-D grid with XCD-aware decode. Requires M/128 % 8 == 0.
// ---------------------------------------------------------------------------
template <int MODE>
__global__ __launch_bounds__(512) void gemm_mfma(
    const bf16_t* __restrict__ A, const bf16_t* __restrict__ WT,
    const float* __restrict__ bias, bf16_t* __restrict__ C,
    int M, int N, int K, int lda, int ldc,
    float* __restrict__ zbuf, int zn)
{
    __shared__ __align__(16) bf16_t Bs[256 * 64];   // 32 KB
    const int tid = threadIdx.x;
    const int wave = tid >> 6, lane = tid & 63;

    if (zbuf) {                                     // side-task: zero KV
        const int zi = blockIdx.x * 512 + tid;
        if (zi < zn) zbuf[zi] = 0.f;
    }

    // XCD-aware decode (identity when N==256)
    const int Nn = N >> 8;
    const int id = blockIdx.x;
    const int s = id >> 3;
    const int bm = ((id & 7) + ((s / Nn) << 3)) * 128;
    const int bn = (s % Nn) * 256;

    const int quad = lane >> 4, mr = lane & 15;
    const int mxor = mr & 7;
    const int wm0 = (wave & 1) * 64;       // m-half
    const int wn0 = (wave >> 1) * 64;      // n-quarter

    // per-lane A row base pointers (4 fragment rows)
    const bf16_t* arow[4];
#pragma unroll
    for (int i = 0; i < 4; i++)
        arow[i] = A + (size_t)(bm + wm0 + i * 16 + mr) * lda;

    float4v acc[4][4];
#pragma unroll
    for (int i = 0; i < 4; i++)
#pragma unroll
        for (int j = 0; j < 4; j++) acc[i][j] = (float4v)(0.f);

    for (int k0 = 0; k0 < K; k0 += 64) {
#pragma unroll
        for (int it = 0; it < 4; it++) {            // B: 2048 chunks
            const int c = it * 512 + tid;
            const int r = c >> 3;
            const int kofs = ((c & 7) ^ (r & 7)) * 8;
            GLOAD_LDS16(WT + (size_t)(bn + r) * K + k0 + kofs, &Bs[c * 8]);
        }
        __syncthreads();
#pragma unroll
        for (int kk = 0; kk < 8; kk += 4) {
            short8 a[4], b[4];
#pragma unroll
            for (int i = 0; i < 4; i++)
                a[i] = *(const short8*)&arow[i][k0 + (quad + kk) * 8];
#pragma unroll
            for (int j = 0; j < 4; j++)
                b[j] = *(const short8*)&Bs[((wn0 + j * 16 + mr) * 8 + ((quad + kk) ^ mxor)) * 8];
#pragma unroll
            for (int i = 0; i < 4; i++)
#pragma unroll
                for (int j = 0; j < 4; j++)
                    acc[i][j] = __builtin_amdgcn_mfma_f32_16x16x32_bf16(
                        a[i], b[j], acc[i][j], 0, 0, 0);
        }
        __syncthreads();
    }

    float bcol[4];
#pragma unroll
    for (int j = 0; j < 4; j++) bcol[j] = bias[bn + wn0 + j * 16 + mr];
#pragma unroll
    for (int i = 0; i < 4; i++) {
#pragma unroll
        for (int r = 0; r < 4; r++) {
            const int grow = bm + wm0 + i * 16 + quad * 4 + r;
            bf16_t* crow = C + (size_t)grow * ldc + bn + wn0 + mr;
#pragma unroll
            for (int j = 0; j < 4; j++) {
                float v = acc[i][j][r] + bcol[j];
                if (MODE == 1) v = fmaxf(v, 0.f);
                crow[j * 16] = f2b(v);
            }
        }
    }
}

// ---------------------------------------------------------------------------
// Pipelined v2 core + fused LayerNorm epilogue (r19, proven for LN GEMMs):
// out = LN(2*(A@W + bias)) * sc + bi.  N=256 fixed, 256 rows/block.
// Used for Wo+LN1 (K=256) and FF2+LN2 (K=1024).
// ---------------------------------------------------------------------------
__global__ __launch_bounds__(512, 2) void gemm_pipe2_ln(
    const bf16_t* __restrict__ A, const bf16_t* __restrict__ WT,
    const float* __restrict__ bias, const float* __restrict__ sc,
    const float* __restrict__ bi, bf16_t* __restrict__ out,
    int K, int lda)
{
    __shared__ __align__(16) bf16_t As[3][256 * 32];   // 48 KB
    __shared__ __align__(16) bf16_t Bs[3][256 * 32];   // 48 KB
    __shared__ float red[8][128][2];                   // 8 KB
    __shared__ float fin[256][2];                      // 2 KB

    const int tid = threadIdx.x;
    const int wave = tid >> 6, lane = tid & 63;
    const int quad = lane >> 4, mr = lane & 15;
    const int bm = blockIdx.x << 8;                    // *256

    const int wm = (wave & 1) << 7;
    const int wn = (wave >> 1) << 6;

    const int KT = K >> 5;

    float bcol[4], scv[4], biv[4];
#pragma unroll
    for (int j = 0; j < 4; ++j) {
        bcol[j] = bias[wn + j * 16 + mr];
        scv[j]  = sc[wn + j * 16 + mr];
        biv[j]  = bi[wn + j * 16 + mr];
    }
    asm volatile("s_waitcnt vmcnt(0)" ::: "memory");
    __builtin_amdgcn_sched_barrier(0);

    auto stageA = [&](int t) {
        const int k0 = t << 5;
        bf16_t* L = &As[t % 3][0];
#pragma unroll
        for (int it = 0; it < 2; ++it) {
            const int c = it * 512 + tid;
            const int r = c >> 2;
            const int up = ((((r & 1) << 2) | (c & 3)) ^ ((r >> 1) & 7));
            const int grow = ((r >> 1) << 1) | (up >> 2);
            GLOAD_LDS16(A + (size_t)(bm + grow) * lda + k0 + ((up & 3) << 3),
                        L + c * 8);
        }
    };
    auto stageB = [&](int t) {
        const int k0 = t << 5;
        bf16_t* L = &Bs[t % 3][0];
#pragma unroll
        for (int it = 0; it < 2; ++it) {
            const int c = it * 512 + tid;
            const int r = c >> 2;
            const int up = ((((r & 1) << 2) | (c & 3)) ^ ((r >> 1) & 7));
            const int grow = ((r >> 1) << 1) | (up >> 2);
            GLOAD_LDS16(WT + (size_t)grow * K + k0 + ((up & 3) << 3),
                        L + c * 8);
        }
    };

    float4v acc[8][4];
#pragma unroll
    for (int i = 0; i < 8; i++)
#pragma unroll
        for (int j = 0; j < 4; j++) acc[i][j] = (float4v)(0.f);

    const int P = KT < 2 ? KT : 2;
    for (int tt = 0; tt < P; ++tt) { stageA(tt); stageB(tt); }

    for (int t = 0; t < KT; ++t) {
        if (t < KT - 1) { WAITV(4); } else { WAITV(0); }
        SBAR();
        __builtin_amdgcn_sched_barrier(0);
        const bf16_t* LA = &As[t % 3][0];
        const bf16_t* LB = &Bs[t % 3][0];
        short8 a0[4], a1[4], b[4];
#pragma unroll
        for (int j = 0; j < 4; ++j) b[j]  = FRAG16(LB, wn + j * 16 + mr);
#pragma unroll
        for (int i = 0; i < 4; ++i) a0[i] = FRAG16(LA, wm + i * 16 + mr);
#pragma unroll
        for (int i = 0; i < 4; ++i) a1[i] = FRAG16(LA, wm + 64 + i * 16 + mr);
        if (t + 2 < KT) { stageA(t + 2); stageB(t + 2); }
        __builtin_amdgcn_s_setprio(1);
        __builtin_amdgcn_sched_barrier(0);
#pragma unroll
        for (int i = 0; i < 4; ++i)
#pragma unroll
            for (int j = 0; j < 4; ++j)
                acc[i][j] = __builtin_amdgcn_mfma_f32_16x16x32_bf16(
                    a0[i], b[j], acc[i][j], 0, 0, 0);
#pragma unroll
        for (int i = 0; i < 4; ++i)
#pragma unroll
            for (int j = 0; j < 4; ++j)
                acc[4 + i][j] = __builtin_amdgcn_mfma_f32_16x16x32_bf16(
                    a1[i], b[j], acc[4 + i][j], 0, 0, 0);
        __builtin_amdgcn_sched_barrier(0);
        __builtin_amdgcn_s_setprio(0);
    }

#pragma unroll
    for (int i = 0; i < 8; ++i) {
#pragma unroll
        for (int r = 0; r < 4; ++r) {
            float ss = 0.f, s2 = 0.f;
#pragma unroll
            for (int j = 0; j < 4; ++j) {
                const float v = 2.0f * (acc[i][j][r] + bcol[j]);
                ss += v; s2 += v * v;
            }
#pragma unroll
            for (int off = 1; off < 16; off <<= 1) {
                ss += __shfl_xor(ss, off, 64);
                s2 += __shfl_xor(s2, off, 64);
            }
            if (mr == 0) {
                const int rl = i * 16 + quad * 4 + r;
                red[wave][rl][0] = ss;
                red[wave][rl][1] = s2;
            }
        }
    }
    __syncthreads();
    {
        const int R = tid >> 1, p = tid & 1;
        const int mh = R >> 7, rl = R & 127;
        fin[R][p] = red[mh][rl][p] + red[mh + 2][rl][p]
                  + red[mh + 4][rl][p] + red[mh + 6][rl][p];
    }
    __syncthreads();

#pragma unroll
    for (int i = 0; i < 8; ++i) {
#pragma unroll
        for (int r = 0; r < 4; ++r) {
            const int R = wm + i * 16 + quad * 4 + r;
            const float mean = fin[R][0] * (1.0f / 256.0f);
            const float var  = fin[R][1] * (1.0f / 256.0f) - mean * mean;
            const float rs = rsqrtf(var + LNEPS_F);
            bf16_t* crow = out + (size_t)(bm + R) * 256 + wn + mr;
#pragma unroll
            for (int j = 0; j < 4; ++j) {
                const float v = 2.0f * (acc[i][j][r] + bcol[j]);
                crow[j * 16] = f2b((v - mean) * rs * scv[j] + biv[j]);
            }
        }
    }
}

// ---------------------------------------------------------------------------
// FAVOR A-gen (standalone, proven): Afav = (qp @ kv) / (qp @ kps).
// ---------------------------------------------------------------------------
__global__ __launch_bounds__(512) void favor_a_kernel(
    const bf16_t* __restrict__ QKV, const float* __restrict__ KV,
    bf16_t* __restrict__ Afav)
{
    __shared__ __align__(16) bf16_t kvT[NHEAD * 34 * 36];   // 19.1 KB

    const int tid = threadIdx.x;
    const int wave = tid >> 6, lane = tid & 63;
    const int bm = blockIdx.x * 128;
    const int b = bm >> 12;
    const int quad = lane >> 4, mr = lane & 15;

    for (int e = tid; e < NHEAD * 34 * 32; e += 512) {
        const int h = e / (34 * 32);
        const int rem = e - h * (34 * 32);
        const int d = rem >> 5, m = rem & 31;
        bf16_t v = 0;
        if (d < 33) v = f2b(KV[((size_t)(b * NHEAD + h)) * (32 * 33) + m * 33 + d]);
        kvT[(h * 34 + d) * 36 + m] = v;
    }
    __syncthreads();

    const int Rrow = bm + wave * 16 + mr;
    const size_t abase = (size_t)(bm + wave * 16) * 256;

    short8 araw[NHEAD];
#pragma unroll
    for (int h = 0; h < NHEAD; ++h)
        araw[h] = *(const short8*)(QKV + (size_t)Rrow * 768 + h * 32 + quad * 8);

#pragma unroll
    for (int h = 0; h < NHEAD; ++h) {
        short8 a;
#pragma unroll
        for (int j = 0; j < 8; j++)
            a[j] = (short)f2b(fmaxf(b2f((bf16_t)araw[h][j]), 0.f) + KEPS_F);
        short8 bf0 = *(const short8*)&kvT[(h * 34 + mr) * 36 + quad * 8];
        short8 bf1 = *(const short8*)&kvT[(h * 34 + 16 + mr) * 36 + quad * 8];
        short8 bden;
#pragma unroll
        for (int j = 0; j < 8; j++) bden[j] = 0;
        if (mr == 0)
            bden = *(const short8*)&kvT[(h * 34 + 32) * 36 + quad * 8];
        float4v c0 = __builtin_amdgcn_mfma_f32_16x16x32_bf16(a, bf0, (float4v)(0.f), 0, 0, 0);
        float4v c1 = __builtin_amdgcn_mfma_f32_16x16x32_bf16(a, bf1, (float4v)(0.f), 0, 0, 0);
        float4v c2 = __builtin_amdgcn_mfma_f32_16x16x32_bf16(a, bden, (float4v)(0.f), 0, 0, 0);
#pragma unroll
        for (int r = 0; r < 4; r++) {
            const float den = __shfl(c2[r], quad << 4);
            const float rinv = 1.0f / den;
            const int rl = quad * 4 + r;
            Afav[abase + (size_t)rl * 256 + h * 32 + mr]      = f2b(c0[r] * rinv);
            Afav[abase + (size_t)rl * 256 + h * 32 + 16 + mr] = f2b(c1[r] * rinv);
        }
    }
}

// ---------------------------------------------------------------------------
// FAVOR kv state via MFMA. Per (b,h): KV[32x33] = kp^T[32xL] @ [V|1][Lx33].
// (KV is zeroed by the QKV GEMM's entry side-task.)
// ---------------------------------------------------------------------------
__global__ __launch_bounds__(256) void kv_mfma(
    const bf16_t* __restrict__ QKV, float* __restrict__ KV)
{
    __shared__ __align__(16) char smem[24576];
    bf16_t (*kp)[36] = (bf16_t(*)[36])smem;                 // 128x36x2 = 9216 B
    bf16_t (*vv)[52] = (bf16_t(*)[52])(smem + 9216);        // 128x52x2 = 13312 B
    float (*red)[6][64][4] = (float(*)[6][64][4])smem;      // 24576 B (aliases)

    const int bh = blockIdx.x;
    const int b = bh >> 3, h = bh & 7;
    const size_t rowbase = (size_t)b * LSEQ + blockIdx.y * 512;
    const int tid = threadIdx.x;
    const int wave = tid >> 6, lane = tid & 63;
    const int quad = lane >> 4, mr = lane & 15;

    for (int e = tid; e < 128 * 20; e += 256) {
        const int l = e / 20, c = 32 + (e % 20);
        vv[l][c] = (c == 32) ? (bf16_t)0x3F80 : (bf16_t)0;
    }

    float4v acc[2][3];
#pragma unroll
    for (int i = 0; i < 2; i++)
#pragma unroll
        for (int t = 0; t < 3; t++) acc[i][t] = (float4v)(0.f);

    for (int pass = 0; pass < 4; pass++) {
        __syncthreads();
        const size_t lp = rowbase + pass * 128;
#pragma unroll
        for (int it = 0; it < 4; it++) {
            const int e = tid + it * 256;
            const int l = e >> 3, c0 = (e & 7) * 4;
            const bf16_t* src = QKV + (lp + l) * 768 + 256 + h * 32 + c0;
            ushort4 kq = *(const ushort4*)src;
            ushort4 vq = *(const ushort4*)(src + 256);
            ushort4 ko;
            ko.x = f2b(fmaxf(b2f(kq.x), 0.f) + KEPS_F);
            ko.y = f2b(fmaxf(b2f(kq.y), 0.f) + KEPS_F);
            ko.z = f2b(fmaxf(b2f(kq.z), 0.f) + KEPS_F);
            ko.w = f2b(fmaxf(b2f(kq.w), 0.f) + KEPS_F);
            *(ushort4*)&kp[l][c0] = ko;
            *(ushort4*)&vv[l][c0] = vq;
        }
        __syncthreads();

        const int lw = wave * 32 + quad * 8;
        short8 a[2], bb[3];
#pragma unroll
        for (int i = 0; i < 2; i++)
#pragma unroll
            for (int j = 0; j < 8; j++)
                a[i][j] = (short)kp[lw + j][i * 16 + mr];
#pragma unroll
        for (int t = 0; t < 3; t++)
#pragma unroll
            for (int j = 0; j < 8; j++)
                bb[t][j] = (short)vv[lw + j][t * 16 + mr];
#pragma unroll
        for (int i = 0; i < 2; i++)
#pragma unroll
            for (int t = 0; t < 3; t++)
                acc[i][t] = __builtin_amdgcn_mfma_f32_16x16x32_bf16(
                    a[i], bb[t], acc[i][t], 0, 0, 0);
    }

    __syncthreads();
#pragma unroll
    for (int i = 0; i < 2; i++)
#pragma unroll
        for (int t = 0; t < 3; t++)
#pragma unroll
            for (int r = 0; r < 4; r++)
                red[wave][i * 3 + t][lane][r] = acc[i][t][r];
    __syncthreads();

    float* dst = KV + (size_t)bh * (32 * 33);
    for (int e = tid; e < 6 * 64 * 4; e += 256) {
        const int t = e >> 8, li = (e >> 2) & 63, r = e & 3;
        const float s = red[0][t][li][r] + red[1][t][li][r]
                      + red[2][t][li][r] + red[3][t][li][r];
        const int i = t / 3, j = t % 3;
        const int m = i * 16 + (li >> 4) * 4 + r;
        const int d = j * 16 + (li & 15);
        if (d < 33) atomicAdd(&dst[m * 33 + d], s);
    }
}

// ---------------------------------------------------------------------------
// Head (fp32 out): out[0:4096] = x[:,0,:] ; out[4096:4608] = x@qpW + qpb
// ---------------------------------------------------------------------------
__global__ __launch_bounds__(256) void head_kernel(
    const bf16_t* __restrict__ X, const float* __restrict__ qpW,
    const float* __restrict__ qpb, float* __restrict__ out)
{
    const int b = blockIdx.x, j = threadIdx.x;
    __shared__ float xr[HIDD];
    float v = b2f(X[((size_t)b * LSEQ) * HIDD + j]);
    xr[j] = v;
    out[b * HIDD + j] = v;
    __syncthreads();
    if (j < 32) {
        float acc = qpb[j];
        for (int d = 0; d < HIDD; d++)
            acc = fmaf(xr[d], qpW[d * 32 + j], acc);
        out[NB * HIDD + b * 32 + j] = acc;
    }
}

// ---------------------------------------------------------------------------
extern "C" void kernel_launch(void* const* d_in, const int* in_sizes, int n_in,
                              void* d_out, int out_size, void* d_ws, size_t ws_size,
                              hipStream_t stream)
{
    const float* hidden = (const float*)d_in[0];
    const float* ins    = (const float*)d_in[1];
    const int*   resets = (const int*)d_in[2];
    const float* embW   = (const float*)d_in[3];
    const float* embb   = (const float*)d_in[4];
    const float* Wq = (const float*)d_in[5];
    const float* bq = (const float*)d_in[6];
    const float* Wk = (const float*)d_in[7];
    const float* bk = (const float*)d_in[8];
    const float* Wv = (const float*)d_in[9];
    const float* bv = (const float*)d_in[10];
    const float* Wo = (const float*)d_in[11];
    const float* bo = (const float*)d_in[12];
    const float* ln1s = (const float*)d_in[13];
    const float* ln1b = (const float*)d_in[14];
    const float* W1 = (const float*)d_in[15];
    const float* b1 = (const float*)d_in[16];
    const float* W2 = (const float*)d_in[17];
    const float* b2 = (const float*)d_in[18];
    const float* ln2s = (const float*)d_in[19];
    const float* ln2b = (const float*)d_in[20];
    const float* qpW = (const float*)d_in[21];
    const float* qpb = (const float*)d_in[22];

    // ---- workspace (~195 MB < 256 MiB) ----
    const size_t ACT_SZ = (size_t)MROWS * HIDD;            // 16.78M elems
    bf16_t* X    = (bf16_t*)d_ws;                          // 33.5 MB
    bf16_t* QKV  = X + ACT_SZ;                             // 65536x768 = 100.7 MB
    bf16_t* H1   = QKV;                                    // alias: 65536x1024 (134 MB span)
    bf16_t* Ain  = QKV;                                    // alias (pre-layer only)
    bf16_t* Afav = QKV + (size_t)MROWS * 768;              // spare tail of H1 span, 33.5 MB
    float*  KV   = (float*)(QKV + (size_t)MROWS * FFD);    // after H1 span
    float*  bqkv = KV + KV_ELEMS;                          // 4x768 f32
    bf16_t* WqkvT = (bf16_t*)(bqkv + NLAY * 768);          // [l][768][256]
    bf16_t* WoT   = WqkvT + (size_t)NLAY * 3 * HIDD * HIDD;
    bf16_t* W1T   = WoT + (size_t)NLAY * HIDD * HIDD;
    bf16_t* W2T   = W1T + (size_t)NLAY * HIDD * FFD;
    bf16_t* embWT = W2T + (size_t)NLAY * FFD * HIDD;

    const dim3 blk(256);
    const dim3 blk512(512);
    const size_t HH = (size_t)HIDD * HIDD;

    // ALL weight prep in one dispatch
    prep_all<<<dim3(3108), blk, 0, stream>>>(
        Wq, Wk, Wv, Wo, W1, W2, embW, bq, bk, bv,
        WqkvT, WoT, W1T, W2T, embWT, bqkv);

    prep_a_kernel<<<MROWS / 2, blk, 0, stream>>>(ins, Ain);
    // embed: M=65536, N=256, K=128 -> 512 blocks (Nn=1)
    gemm_mfma<0><<<dim3(512), blk512, 0, stream>>>(Ain, embWT, embb, X, MROWS, HIDD, 128, 128, HIDD,
                                                   nullptr, 0);
    fix_row0_kernel<<<NB, blk, 0, stream>>>(hidden, resets, X);

    for (int l = 0; l < NLAY; l++) {
        // fused QKV projection (+ KV zero side-task):
        // X[M][256] @ Wqkv[256][768] -> QKV[M][768]
        gemm_mfma<0><<<dim3(512 * 3), blk512, 0, stream>>>(X, WqkvT + (size_t)l * 3 * HH,
                                                           bqkv + l * 768, QKV, MROWS, 768, HIDD, HIDD, 768,
                                                           KV, KV_ELEMS);

        kv_mfma<<<dim3(NB * NHEAD, 8), blk, 0, stream>>>(QKV, KV);

        // favor A-gen -> Afav (standalone, latency-tolerant)
        favor_a_kernel<<<dim3(MROWS / 128), blk512, 0, stream>>>(QKV, KV, Afav);

        // Wo + residual-doubling + LN1 via pipelined GEMM v2 (K=256) -> X
        gemm_pipe2_ln<<<dim3(256), blk512, 0, stream>>>(
            Afav, WoT + (size_t)l * HH, bo + l * HIDD,
            ln1s + l * HIDD, ln1b + l * HIDD, X, HIDD, HIDD);

        // FF1 (A-direct core): X @ W1 -> H1 (over dead QKV region + spare)
        gemm_mfma<1><<<dim3(512 * 4), blk512, 0, stream>>>(X, W1T + (size_t)l * HIDD * FFD,
                                                           b1 + l * FFD, H1, MROWS, FFD, HIDD, HIDD, FFD,
                                                           nullptr, 0);
        // FF2 + residual-doubling + LN2 fused -> X (pipelined v2, K=1024)
        gemm_pipe2_ln<<<dim3(256), blk512, 0, stream>>>(
            H1, W2T + (size_t)l * FFD * HIDD, b2 + l * HIDD,
            ln2s + l * HIDD, ln2b + l * HIDD, X, FFD, FFD);
    }

    head_kernel<<<NB, blk, 0, stream>>>(X, qpW, qpb, (float*)d_out);
}

// Round 12
// 999.134 us; speedup vs baseline: 1.2135x; 1.2135x over previous
//
#include <hip/hip_runtime.h>

// ---------------------------------------------------------------------------
// TransformerAgent (Performer/FAVOR+ encoder), MI355X gfx950.
// Round 26: REVERT r25's A-direct (REFUTED: 16-lane row-gather on the MFMA
// critical path, FF1 94us vs 52.3; the LDS ring earns its keep) -> back to
// r24 exactly (FF1 52.3us, total 963-972 band, best).
// One low-risk experiment: kv_mfma staging loads 8B->16B (short8, 4 thr/row;
// same 64B/row coalescing, half the load instructions). LDS strides 36->40
// and 52->56 elems (16B-aligned rows; 10240+14336=24576B, same footprint).
// Fragment-gather indices unchanged. Falsifier: total >= 975 -> revert.
// B=16, L=4096(=1+4095), HID=256, NH=8, DH=32, FF=1024, NL=4, ACT=32
// ---------------------------------------------------------------------------

typedef unsigned short bf16_t;
typedef __attribute__((ext_vector_type(8))) short short8;
typedef __attribute__((ext_vector_type(4))) float float4v;

#define NB 16
#define LSEQ 4096
#define MROWS (NB * LSEQ)      // 65536
#define HIDD 256
#define NHEAD 8
#define DHEAD 32
#define FFD 1024
#define NLAY 4
#define KEPS_F 1e-3f
#define LNEPS_F 1e-6f
#define KV_ELEMS (NB * NHEAD * 32 * 33)   // 135168

__device__ __forceinline__ float b2f(bf16_t h) {
    return __uint_as_float(((unsigned int)h) << 16);
}
__device__ __forceinline__ bf16_t f2b(float f) {
    unsigned int u = __float_as_uint(f);
    u += 0x7fffu + ((u >> 16) & 1u);   // round-to-nearest-even
    return (bf16_t)(u >> 16);
}

// async global->LDS, 16B per lane
#define GLOAD_LDS16(g, l)                                                     \
    __builtin_amdgcn_global_load_lds(                                         \
        (const __attribute__((address_space(1))) void*)(g),                   \
        (__attribute__((address_space(3))) void*)(l), 16, 0, 0)

// raw barrier + counted waits (used by the pipe2_ln core)
#define SBAR() __builtin_amdgcn_s_barrier()
#define WAITV(n)                                                              \
    do {                                                                      \
        asm volatile("s_waitcnt vmcnt(" #n ")" ::: "memory");                 \
        __builtin_amdgcn_sched_barrier(0);                                    \
    } while (0)

// pipe2_ln fragment read: (row R, k-chunk quad) of a [256]x32 panel in
// pair-row-XOR-swizzled chunk order.
#define FRAG16(L, R)                                                          \
    (*(const short8*)&(L)[((((R) >> 1) * 8) +                                  \
        (((((R) & 1) << 2) | quad) ^ (((R) >> 1) & 7))) * 8])

// ---------------------------------------------------------------------------
// prep_all: ALL weight transposes + bias concat in ONE dispatch.
// Flat decode over 3108 blocks (tile math byte-identical to the proven
// conv_transpose_kernel).
// ---------------------------------------------------------------------------
__global__ __launch_bounds__(256) void prep_all(
    const float* __restrict__ Wq, const float* __restrict__ Wk,
    const float* __restrict__ Wv, const float* __restrict__ Wo,
    const float* __restrict__ W1, const float* __restrict__ W2,
    const float* __restrict__ embW,
    const float* __restrict__ bq, const float* __restrict__ bk,
    const float* __restrict__ bv,
    bf16_t* __restrict__ WqkvT, bf16_t* __restrict__ WoT,
    bf16_t* __restrict__ W1T, bf16_t* __restrict__ W2T,
    bf16_t* __restrict__ embWT, float* __restrict__ bqkv)
{
    const int id = blockIdx.x;
    if (id >= 3104) {                          // concat_bias: 4 blocks
        const int l = id - 3104, j = threadIdx.x;
        bqkv[l * 768 + j]       = bq[l * 256 + j];
        bqkv[l * 768 + 256 + j] = bk[l * 256 + j];
        bqkv[l * 768 + 512 + j] = bv[l * 256 + j];
        return;
    }
    const float* in; bf16_t* out;
    int R, C, z, x, y; size_t ils, ols;
    if (id < 1024) {
        const int seg = id >> 8;               // 0..3: Wq,Wk,Wv,Wo
        const int t = id & 255;
        z = t >> 6; const int tt = t & 63; x = tt & 7; y = tt >> 3;
        R = 256; C = 256; ils = 65536;
        if (seg == 0)      { in = Wq; out = WqkvT;              ols = 3 * 65536; }
        else if (seg == 1) { in = Wk; out = WqkvT + 65536;      ols = 3 * 65536; }
        else if (seg == 2) { in = Wv; out = WqkvT + 2 * 65536;  ols = 3 * 65536; }
        else               { in = Wo; out = WoT;                ols = 65536;     }
    } else if (id < 2048) {
        const int t2 = id - 1024; z = t2 >> 8; const int t = t2 & 255;
        x = t & 31; y = t >> 5; R = 256; C = 1024; ils = ols = 262144;
        in = W1; out = W1T;
    } else if (id < 3072) {
        const int t2 = id - 2048; z = t2 >> 8; const int t = t2 & 255;
        x = t & 7; y = t >> 3; R = 1024; C = 256; ils = ols = 262144;
        in = W2; out = W2T;
    } else {
        const int t = id - 3072; z = 0; x = t & 7; y = t >> 3;
        R = 128; C = 256; ils = 0; ols = 0;
        in = embW; out = embWT;
    }
    __shared__ float tile[32][33];
    const size_t ib = (size_t)z * ils;
    const size_t ob = (size_t)z * ols;
    const int r0 = y * 32, c0 = x * 32;
    const int tx = threadIdx.x & 31, ty = threadIdx.x >> 5;   // 32 x 8
#pragma unroll
    for (int rr = ty; rr < 32; rr += 8)
        tile[rr][tx] = in[ib + (size_t)(r0 + rr) * C + c0 + tx];
    __syncthreads();
#pragma unroll
    for (int rr = ty; rr < 32; rr += 8)
        out[ob + (size_t)(c0 + rr) * R + r0 + tx] = f2b(tile[tx][rr]);
}

// ---------------------------------------------------------------------------
// Embed A-prep: Ain[b*4096+l][128] = (l==0) ? 0 : bf16(ins[b][l-1][:])
// ---------------------------------------------------------------------------
__global__ __launch_bounds__(256) void prep_a_kernel(
    const float* __restrict__ ins, bf16_t* __restrict__ Ain)
{
    const int row = blockIdx.x * 2 + (threadIdx.x >> 7);
    const int j = threadIdx.x & 127;
    const int b = row >> 12, l = row & (LSEQ - 1);
    bf16_t v = 0;
    if (l != 0) v = f2b(ins[((size_t)b * 4095 + (l - 1)) * 128 + j]);
    Ain[(size_t)row * 128 + j] = v;
}

// X[b,0,:] = resets ? 0 : hidden
__global__ __launch_bounds__(256) void fix_row0_kernel(
    const float* __restrict__ hidden, const int* __restrict__ resets,
    bf16_t* __restrict__ X)
{
    const int b = blockIdx.x, j = threadIdx.x;
    float v = resets[b] ? 0.f : hidden[b * HIDD + j];
    X[((size_t)b * LSEQ) * HIDD + j] = f2b(v);
}

// ---------------------------------------------------------------------------
// MFMA GEMM (r14/r22/r24, proven fastest): C = act(A @ W + bias); WT[N][K].
// 512 thr = 8 waves, block 128x256, wave 64x64 (2m x 4n). XOR-swizzled LDS.
// Optional side-task: zero zbuf[0..zn) at entry (QKV instantiation zeroes KV).
// 1-D grid with XCD-aware decode. Requires M/128 % 8 == 0.
// ---------------------------------------------------------------------------
template <int MODE>
__global__ __launch_bounds__(512) void gemm_mfma(
    const bf16_t* __restrict__ A, const bf16_t* __restrict__ WT,
    const float* __restrict__ bias, bf16_t* __restrict__ C,
    int M, int N, int K, int lda, int ldc,
    float* __restrict__ zbuf, int zn)
{
    __shared__ __align__(16) bf16_t As[128 * 64];   // 16 KB
    __shared__ __align__(16) bf16_t Bs[256 * 64];   // 32 KB
    const int tid = threadIdx.x;
    const int wave = tid >> 6, lane = tid & 63;

    if (zbuf) {                                     // side-task: zero KV
        const int zi = blockIdx.x * 512 + tid;
        if (zi < zn) zbuf[zi] = 0.f;
    }

    // XCD-aware decode (identity when N==256)
    const int Nn = N >> 8;
    const int id = blockIdx.x;
    const int s = id >> 3;
    const int bm = ((id & 7) + ((s / Nn) << 3)) * 128;
    const int bn = (s % Nn) * 256;

    const int quad = lane >> 4, mr = lane & 15;
    const int mxor = mr & 7;
    const int wm0 = (wave & 1) * 64;       // m-half
    const int wn0 = (wave >> 1) * 64;      // n-quarter

    float4v acc[4][4];
#pragma unroll
    for (int i = 0; i < 4; i++)
#pragma unroll
        for (int j = 0; j < 4; j++) acc[i][j] = (float4v)(0.f);

    for (int k0 = 0; k0 < K; k0 += 64) {
#pragma unroll
        for (int it = 0; it < 2; it++) {            // A: 1024 chunks
            const int c = it * 512 + tid;
            const int r = c >> 3;
            const int kofs = ((c & 7) ^ (r & 7)) * 8;
            GLOAD_LDS16(A + (size_t)(bm + r) * lda + k0 + kofs, &As[c * 8]);
        }
#pragma unroll
        for (int it = 0; it < 4; it++) {            // B: 2048 chunks
            const int c = it * 512 + tid;
            const int r = c >> 3;
            const int kofs = ((c & 7) ^ (r & 7)) * 8;
            GLOAD_LDS16(WT + (size_t)(bn + r) * K + k0 + kofs, &Bs[c * 8]);
        }
        __syncthreads();
#pragma unroll
        for (int kk = 0; kk < 8; kk += 4) {
            short8 a[4], b[4];
#pragma unroll
            for (int i = 0; i < 4; i++)
                a[i] = *(const short8*)&As[((wm0 + i * 16 + mr) * 8 + ((quad + kk) ^ mxor)) * 8];
#pragma unroll
            for (int j = 0; j < 4; j++)
                b[j] = *(const short8*)&Bs[((wn0 + j * 16 + mr) * 8 + ((quad + kk) ^ mxor)) * 8];
#pragma unroll
            for (int i = 0; i < 4; i++)
#pragma unroll
                for (int j = 0; j < 4; j++)
                    acc[i][j] = __builtin_amdgcn_mfma_f32_16x16x32_bf16(
                        a[i], b[j], acc[i][j], 0, 0, 0);
        }
        __syncthreads();
    }

    float bcol[4];
#pragma unroll
    for (int j = 0; j < 4; j++) bcol[j] = bias[bn + wn0 + j * 16 + mr];
#pragma unroll
    for (int i = 0; i < 4; i++) {
#pragma unroll
        for (int r = 0; r < 4; r++) {
            const int grow = bm + wm0 + i * 16 + quad * 4 + r;
            bf16_t* crow = C + (size_t)grow * ldc + bn + wn0 + mr;
#pragma unroll
            for (int j = 0; j < 4; j++) {
                float v = acc[i][j][r] + bcol[j];
                if (MODE == 1) v = fmaxf(v, 0.f);
                crow[j * 16] = f2b(v);
            }
        }
    }
}

// ---------------------------------------------------------------------------
// Pipelined v2 core + fused LayerNorm epilogue (r19, proven for LN GEMMs):
// out = LN(2*(A@W + bias)) * sc + bi.  N=256 fixed, 256 rows/block.
// Used for Wo+LN1 (K=256) and FF2+LN2 (K=1024).
// ---------------------------------------------------------------------------
__global__ __launch_bounds__(512, 2) void gemm_pipe2_ln(
    const bf16_t* __restrict__ A, const bf16_t* __restrict__ WT,
    const float* __restrict__ bias, const float* __restrict__ sc,
    const float* __restrict__ bi, bf16_t* __restrict__ out,
    int K, int lda)
{
    __shared__ __align__(16) bf16_t As[3][256 * 32];   // 48 KB
    __shared__ __align__(16) bf16_t Bs[3][256 * 32];   // 48 KB
    __shared__ float red[8][128][2];                   // 8 KB
    __shared__ float fin[256][2];                      // 2 KB

    const int tid = threadIdx.x;
    const int wave = tid >> 6, lane = tid & 63;
    const int quad = lane >> 4, mr = lane & 15;
    const int bm = blockIdx.x << 8;                    // *256

    const int wm = (wave & 1) << 7;
    const int wn = (wave >> 1) << 6;

    const int KT = K >> 5;

    float bcol[4], scv[4], biv[4];
#pragma unroll
    for (int j = 0; j < 4; ++j) {
        bcol[j] = bias[wn + j * 16 + mr];
        scv[j]  = sc[wn + j * 16 + mr];
        biv[j]  = bi[wn + j * 16 + mr];
    }
    asm volatile("s_waitcnt vmcnt(0)" ::: "memory");
    __builtin_amdgcn_sched_barrier(0);

    auto stageA = [&](int t) {
        const int k0 = t << 5;
        bf16_t* L = &As[t % 3][0];
#pragma unroll
        for (int it = 0; it < 2; ++it) {
            const int c = it * 512 + tid;
            const int r = c >> 2;
            const int up = ((((r & 1) << 2) | (c & 3)) ^ ((r >> 1) & 7));
            const int grow = ((r >> 1) << 1) | (up >> 2);
            GLOAD_LDS16(A + (size_t)(bm + grow) * lda + k0 + ((up & 3) << 3),
                        L + c * 8);
        }
    };
    auto stageB = [&](int t) {
        const int k0 = t << 5;
        bf16_t* L = &Bs[t % 3][0];
#pragma unroll
        for (int it = 0; it < 2; ++it) {
            const int c = it * 512 + tid;
            const int r = c >> 2;
            const int up = ((((r & 1) << 2) | (c & 3)) ^ ((r >> 1) & 7));
            const int grow = ((r >> 1) << 1) | (up >> 2);
            GLOAD_LDS16(WT + (size_t)grow * K + k0 + ((up & 3) << 3),
                        L + c * 8);
        }
    };

    float4v acc[8][4];
#pragma unroll
    for (int i = 0; i < 8; i++)
#pragma unroll
        for (int j = 0; j < 4; j++) acc[i][j] = (float4v)(0.f);

    const int P = KT < 2 ? KT : 2;
    for (int tt = 0; tt < P; ++tt) { stageA(tt); stageB(tt); }

    for (int t = 0; t < KT; ++t) {
        if (t < KT - 1) { WAITV(4); } else { WAITV(0); }
        SBAR();
        __builtin_amdgcn_sched_barrier(0);
        const bf16_t* LA = &As[t % 3][0];
        const bf16_t* LB = &Bs[t % 3][0];
        short8 a0[4], a1[4], b[4];
#pragma unroll
        for (int j = 0; j < 4; ++j) b[j]  = FRAG16(LB, wn + j * 16 + mr);
#pragma unroll
        for (int i = 0; i < 4; ++i) a0[i] = FRAG16(LA, wm + i * 16 + mr);
#pragma unroll
        for (int i = 0; i < 4; ++i) a1[i] = FRAG16(LA, wm + 64 + i * 16 + mr);
        if (t + 2 < KT) { stageA(t + 2); stageB(t + 2); }
        __builtin_amdgcn_s_setprio(1);
        __builtin_amdgcn_sched_barrier(0);
#pragma unroll
        for (int i = 0; i < 4; ++i)
#pragma unroll
            for (int j = 0; j < 4; ++j)
                acc[i][j] = __builtin_amdgcn_mfma_f32_16x16x32_bf16(
                    a0[i], b[j], acc[i][j], 0, 0, 0);
#pragma unroll
        for (int i = 0; i < 4; ++i)
#pragma unroll
            for (int j = 0; j < 4; ++j)
                acc[4 + i][j] = __builtin_amdgcn_mfma_f32_16x16x32_bf16(
                    a1[i], b[j], acc[4 + i][j], 0, 0, 0);
        __builtin_amdgcn_sched_barrier(0);
        __builtin_amdgcn_s_setprio(0);
    }

#pragma unroll
    for (int i = 0; i < 8; ++i) {
#pragma unroll
        for (int r = 0; r < 4; ++r) {
            float ss = 0.f, s2 = 0.f;
#pragma unroll
            for (int j = 0; j < 4; ++j) {
                const float v = 2.0f * (acc[i][j][r] + bcol[j]);
                ss += v; s2 += v * v;
            }
#pragma unroll
            for (int off = 1; off < 16; off <<= 1) {
                ss += __shfl_xor(ss, off, 64);
                s2 += __shfl_xor(s2, off, 64);
            }
            if (mr == 0) {
                const int rl = i * 16 + quad * 4 + r;
                red[wave][rl][0] = ss;
                red[wave][rl][1] = s2;
            }
        }
    }
    __syncthreads();
    {
        const int R = tid >> 1, p = tid & 1;
        const int mh = R >> 7, rl = R & 127;
        fin[R][p] = red[mh][rl][p] + red[mh + 2][rl][p]
                  + red[mh + 4][rl][p] + red[mh + 6][rl][p];
    }
    __syncthreads();

#pragma unroll
    for (int i = 0; i < 8; ++i) {
#pragma unroll
        for (int r = 0; r < 4; ++r) {
            const int R = wm + i * 16 + quad * 4 + r;
            const float mean = fin[R][0] * (1.0f / 256.0f);
            const float var  = fin[R][1] * (1.0f / 256.0f) - mean * mean;
            const float rs = rsqrtf(var + LNEPS_F);
            bf16_t* crow = out + (size_t)(bm + R) * 256 + wn + mr;
#pragma unroll
            for (int j = 0; j < 4; ++j) {
                const float v = 2.0f * (acc[i][j][r] + bcol[j]);
                crow[j * 16] = f2b((v - mean) * rs * scv[j] + biv[j]);
            }
        }
    }
}

// ---------------------------------------------------------------------------
// FAVOR A-gen (standalone, proven): Afav = (qp @ kv) / (qp @ kps).
// ---------------------------------------------------------------------------
__global__ __launch_bounds__(512) void favor_a_kernel(
    const bf16_t* __restrict__ QKV, const float* __restrict__ KV,
    bf16_t* __restrict__ Afav)
{
    __shared__ __align__(16) bf16_t kvT[NHEAD * 34 * 36];   // 19.1 KB

    const int tid = threadIdx.x;
    const int wave = tid >> 6, lane = tid & 63;
    const int bm = blockIdx.x * 128;
    const int b = bm >> 12;
    const int quad = lane >> 4, mr = lane & 15;

    for (int e = tid; e < NHEAD * 34 * 32; e += 512) {
        const int h = e / (34 * 32);
        const int rem = e - h * (34 * 32);
        const int d = rem >> 5, m = rem & 31;
        bf16_t v = 0;
        if (d < 33) v = f2b(KV[((size_t)(b * NHEAD + h)) * (32 * 33) + m * 33 + d]);
        kvT[(h * 34 + d) * 36 + m] = v;
    }
    __syncthreads();

    const int Rrow = bm + wave * 16 + mr;
    const size_t abase = (size_t)(bm + wave * 16) * 256;

    short8 araw[NHEAD];
#pragma unroll
    for (int h = 0; h < NHEAD; ++h)
        araw[h] = *(const short8*)(QKV + (size_t)Rrow * 768 + h * 32 + quad * 8);

#pragma unroll
    for (int h = 0; h < NHEAD; ++h) {
        short8 a;
#pragma unroll
        for (int j = 0; j < 8; j++)
            a[j] = (short)f2b(fmaxf(b2f((bf16_t)araw[h][j]), 0.f) + KEPS_F);
        short8 bf0 = *(const short8*)&kvT[(h * 34 + mr) * 36 + quad * 8];
        short8 bf1 = *(const short8*)&kvT[(h * 34 + 16 + mr) * 36 + quad * 8];
        short8 bden;
#pragma unroll
        for (int j = 0; j < 8; j++) bden[j] = 0;
        if (mr == 0)
            bden = *(const short8*)&kvT[(h * 34 + 32) * 36 + quad * 8];
        float4v c0 = __builtin_amdgcn_mfma_f32_16x16x32_bf16(a, bf0, (float4v)(0.f), 0, 0, 0);
        float4v c1 = __builtin_amdgcn_mfma_f32_16x16x32_bf16(a, bf1, (float4v)(0.f), 0, 0, 0);
        float4v c2 = __builtin_amdgcn_mfma_f32_16x16x32_bf16(a, bden, (float4v)(0.f), 0, 0, 0);
#pragma unroll
        for (int r = 0; r < 4; r++) {
            const float den = __shfl(c2[r], quad << 4);
            const float rinv = 1.0f / den;
            const int rl = quad * 4 + r;
            Afav[abase + (size_t)rl * 256 + h * 32 + mr]      = f2b(c0[r] * rinv);
            Afav[abase + (size_t)rl * 256 + h * 32 + 16 + mr] = f2b(c1[r] * rinv);
        }
    }
}

// ---------------------------------------------------------------------------
// FAVOR kv state via MFMA. Per (b,h): KV[32x33] = kp^T[32xL] @ [V|1][Lx33].
// (KV zeroed by the QKV GEMM side-task.)
// r26: staging loads vectorized 8B->16B (4 thr/row); LDS strides 36->40 and
// 52->56 elems so 16B stores are aligned (10240+14336 = 24576 B, unchanged).
// ---------------------------------------------------------------------------
__global__ __launch_bounds__(256) void kv_mfma(
    const bf16_t* __restrict__ QKV, float* __restrict__ KV)
{
    __shared__ __align__(16) char smem[24576];
    bf16_t (*kp)[40] = (bf16_t(*)[40])smem;                 // 128x40x2 = 10240 B
    bf16_t (*vv)[56] = (bf16_t(*)[56])(smem + 10240);       // 128x56x2 = 14336 B
    float (*red)[6][64][4] = (float(*)[6][64][4])smem;      // 24576 B (aliases)

    const int bh = blockIdx.x;
    const int b = bh >> 3, h = bh & 7;
    const size_t rowbase = (size_t)b * LSEQ + blockIdx.y * 512;
    const int tid = threadIdx.x;
    const int wave = tid >> 6, lane = tid & 63;
    const int quad = lane >> 4, mr = lane & 15;

    // init vv cols 32..55 (ones-column at 32, zeros elsewhere)
    for (int e = tid; e < 128 * 24; e += 256) {
        const int l = e / 24, c = 32 + (e % 24);
        vv[l][c] = (c == 32) ? (bf16_t)0x3F80 : (bf16_t)0;
    }

    float4v acc[2][3];
#pragma unroll
    for (int i = 0; i < 2; i++)
#pragma unroll
        for (int t = 0; t < 3; t++) acc[i][t] = (float4v)(0.f);

    for (int pass = 0; pass < 4; pass++) {
        __syncthreads();
        const size_t lp = rowbase + pass * 128;
#pragma unroll
        for (int it = 0; it < 2; it++) {               // 512 chunks of 16B
            const int e = tid + it * 256;
            const int l = e >> 2, c0 = (e & 3) * 8;
            const bf16_t* src = QKV + (lp + l) * 768 + 256 + h * 32 + c0;
            short8 kq = *(const short8*)src;
            short8 vq = *(const short8*)(src + 256);
            short8 ko;
#pragma unroll
            for (int j = 0; j < 8; j++)
                ko[j] = (short)f2b(fmaxf(b2f((bf16_t)kq[j]), 0.f) + KEPS_F);
            *(short8*)&kp[l][c0] = ko;
            *(short8*)&vv[l][c0] = vq;
        }
        __syncthreads();

        const int lw = wave * 32 + quad * 8;
        short8 a[2], bb[3];
#pragma unroll
        for (int i = 0; i < 2; i++)
#pragma unroll
            for (int j = 0; j < 8; j++)
                a[i][j] = (short)kp[lw + j][i * 16 + mr];
#pragma unroll
        for (int t = 0; t < 3; t++)
#pragma unroll
            for (int j = 0; j < 8; j++)
                bb[t][j] = (short)vv[lw + j][t * 16 + mr];
#pragma unroll
        for (int i = 0; i < 2; i++)
#pragma unroll
            for (int t = 0; t < 3; t++)
                acc[i][t] = __builtin_amdgcn_mfma_f32_16x16x32_bf16(
                    a[i], bb[t], acc[i][t], 0, 0, 0);
    }

    __syncthreads();
#pragma unroll
    for (int i = 0; i < 2; i++)
#pragma unroll
        for (int t = 0; t < 3; t++)
#pragma unroll
            for (int r = 0; r < 4; r++)
                red[wave][i * 3 + t][lane][r] = acc[i][t][r];
    __syncthreads();

    float* dst = KV + (size_t)bh * (32 * 33);
    for (int e = tid; e < 6 * 64 * 4; e += 256) {
        const int t = e >> 8, li = (e >> 2) & 63, r = e & 3;
        const float s = red[0][t][li][r] + red[1][t][li][r]
                      + red[2][t][li][r] + red[3][t][li][r];
        const int i = t / 3, j = t % 3;
        const int m = i * 16 + (li >> 4) * 4 + r;
        const int d = j * 16 + (li & 15);
        if (d < 33) atomicAdd(&dst[m * 33 + d], s);
    }
}

// ---------------------------------------------------------------------------
// Head (fp32 out): out[0:4096] = x[:,0,:] ; out[4096:4608] = x@qpW + qpb
// ---------------------------------------------------------------------------
__global__ __launch_bounds__(256) void head_kernel(
    const bf16_t* __restrict__ X, const float* __restrict__ qpW,
    const float* __restrict__ qpb, float* __restrict__ out)
{
    const int b = blockIdx.x, j = threadIdx.x;
    __shared__ float xr[HIDD];
    float v = b2f(X[((size_t)b * LSEQ) * HIDD + j]);
    xr[j] = v;
    out[b * HIDD + j] = v;
    __syncthreads();
    if (j < 32) {
        float acc = qpb[j];
        for (int d = 0; d < HIDD; d++)
            acc = fmaf(xr[d], qpW[d * 32 + j], acc);
        out[NB * HIDD + b * 32 + j] = acc;
    }
}

// ---------------------------------------------------------------------------
extern "C" void kernel_launch(void* const* d_in, const int* in_sizes, int n_in,
                              void* d_out, int out_size, void* d_ws, size_t ws_size,
                              hipStream_t stream)
{
    const float* hidden = (const float*)d_in[0];
    const float* ins    = (const float*)d_in[1];
    const int*   resets = (const int*)d_in[2];
    const float* embW   = (const float*)d_in[3];
    const float* embb   = (const float*)d_in[4];
    const float* Wq = (const float*)d_in[5];
    const float* bq = (const float*)d_in[6];
    const float* Wk = (const float*)d_in[7];
    const float* bk = (const float*)d_in[8];
    const float* Wv = (const float*)d_in[9];
    const float* bv = (const float*)d_in[10];
    const float* Wo = (const float*)d_in[11];
    const float* bo = (const float*)d_in[12];
    const float* ln1s = (const float*)d_in[13];
    const float* ln1b = (const float*)d_in[14];
    const float* W1 = (const float*)d_in[15];
    const float* b1 = (const float*)d_in[16];
    const float* W2 = (const float*)d_in[17];
    const float* b2 = (const float*)d_in[18];
    const float* ln2s = (const float*)d_in[19];
    const float* ln2b = (const float*)d_in[20];
    const float* qpW = (const float*)d_in[21];
    const float* qpb = (const float*)d_in[22];

    // ---- workspace (~195 MB < 256 MiB) ----
    const size_t ACT_SZ = (size_t)MROWS * HIDD;            // 16.78M elems
    bf16_t* X    = (bf16_t*)d_ws;                          // 33.5 MB
    bf16_t* QKV  = X + ACT_SZ;                             // 65536x768 = 100.7 MB
    bf16_t* H1   = QKV;                                    // alias: 65536x1024 (134 MB span)
    bf16_t* Ain  = QKV;                                    // alias (pre-layer only)
    bf16_t* Afav = QKV + (size_t)MROWS * 768;              // spare tail of H1 span, 33.5 MB
    float*  KV   = (float*)(QKV + (size_t)MROWS * FFD);    // after H1 span
    float*  bqkv = KV + KV_ELEMS;                          // 4x768 f32
    bf16_t* WqkvT = (bf16_t*)(bqkv + NLAY * 768);          // [l][768][256]
    bf16_t* WoT   = WqkvT + (size_t)NLAY * 3 * HIDD * HIDD;
    bf16_t* W1T   = WoT + (size_t)NLAY * HIDD * HIDD;
    bf16_t* W2T   = W1T + (size_t)NLAY * HIDD * FFD;
    bf16_t* embWT = W2T + (size_t)NLAY * FFD * HIDD;

    const dim3 blk(256);
    const dim3 blk512(512);
    const size_t HH = (size_t)HIDD * HIDD;

    // ALL weight prep in one dispatch
    prep_all<<<dim3(3108), blk, 0, stream>>>(
        Wq, Wk, Wv, Wo, W1, W2, embW, bq, bk, bv,
        WqkvT, WoT, W1T, W2T, embWT, bqkv);

    prep_a_kernel<<<MROWS / 2, blk, 0, stream>>>(ins, Ain);
    // embed: M=65536, N=256, K=128 -> 512 blocks (Nn=1)
    gemm_mfma<0><<<dim3(512), blk512, 0, stream>>>(Ain, embWT, embb, X, MROWS, HIDD, 128, 128, HIDD,
                                                   nullptr, 0);
    fix_row0_kernel<<<NB, blk, 0, stream>>>(hidden, resets, X);

    for (int l = 0; l < NLAY; l++) {
        // fused QKV projection (+ KV zero side-task):
        // X[M][256] @ Wqkv[256][768] -> QKV[M][768]
        gemm_mfma<0><<<dim3(512 * 3), blk512, 0, stream>>>(X, WqkvT + (size_t)l * 3 * HH,
                                                           bqkv + l * 768, QKV, MROWS, 768, HIDD, HIDD, 768,
                                                           KV, KV_ELEMS);

        kv_mfma<<<dim3(NB * NHEAD, 8), blk, 0, stream>>>(QKV, KV);

        // favor A-gen -> Afav (standalone, latency-tolerant)
        favor_a_kernel<<<dim3(MROWS / 128), blk512, 0, stream>>>(QKV, KV, Afav);

        // Wo + residual-doubling + LN1 via pipelined GEMM v2 (K=256) -> X
        gemm_pipe2_ln<<<dim3(256), blk512, 0, stream>>>(
            Afav, WoT + (size_t)l * HH, bo + l * HIDD,
            ln1s + l * HIDD, ln1b + l * HIDD, X, HIDD, HIDD);

        // FF1 (r14 core): X @ W1 -> H1 (over dead QKV region + spare)
        gemm_mfma<1><<<dim3(512 * 4), blk512, 0, stream>>>(X, W1T + (size_t)l * HIDD * FFD,
                                                           b1 + l * FFD, H1, MROWS, FFD, HIDD, HIDD, FFD,
                                                           nullptr, 0);
        // FF2 + residual-doubling + LN2 fused -> X (pipelined v2, K=1024)
        gemm_pipe2_ln<<<dim3(256), blk512, 0, stream>>>(
            H1, W2T + (size_t)l * FFD * HIDD, b2 + l * HIDD,
            ln2s + l * HIDD, ln2b + l * HIDD, X, FFD, FFD);
    }

    head_kernel<<<NB, blk, 0, stream>>>(X, qpW, qpb, (float*)d_out);
}

// Round 13
// 931.626 us; speedup vs baseline: 1.3015x; 1.0725x over previous
//
#include <hip/hip_runtime.h>

// ---------------------------------------------------------------------------
// TransformerAgent (Performer/FAVOR+ encoder), MI355X gfx950.
// Round 27: EXACT r24 (the converged configuration; best family 963-972us).
// r26's kv_mfma 16B-staging reverted per falsifier (total 999 >= 975).
// Session ledger: 11 GEMM-core variants refuted (3 pipelined rings, 256^2
// 1-block, 2x LDS-staged stores, A-direct-from-global, 3 fusions). FF1+FF2
// fusion (biggest remaining traffic lever, 268 MB/layer H1) is blocked by
// LDS capacity: pipelined form needs >=208 KB vs 160 KB; serial form is
// r20's measured failure. r24 components, each proven best-of-breed:
//  - embed/QKV/FF1: r14 2-barrier 128x256 gemm_mfma (52.3us FF1)
//  - Wo-LN/FF2: r19 gemm_pipe2_ln (3-slot ring, counted vmcnt)
//  - favor split (r18), prep_all single dispatch (r23), zero_kv fold (r24)
// B=16, L=4096(=1+4095), HID=256, NH=8, DH=32, FF=1024, NL=4, ACT=32
// ---------------------------------------------------------------------------

typedef unsigned short bf16_t;
typedef __attribute__((ext_vector_type(8))) short short8;
typedef __attribute__((ext_vector_type(4))) float float4v;

#define NB 16
#define LSEQ 4096
#define MROWS (NB * LSEQ)      // 65536
#define HIDD 256
#define NHEAD 8
#define DHEAD 32
#define FFD 1024
#define NLAY 4
#define KEPS_F 1e-3f
#define LNEPS_F 1e-6f
#define KV_ELEMS (NB * NHEAD * 32 * 33)   // 135168

__device__ __forceinline__ float b2f(bf16_t h) {
    return __uint_as_float(((unsigned int)h) << 16);
}
__device__ __forceinline__ bf16_t f2b(float f) {
    unsigned int u = __float_as_uint(f);
    u += 0x7fffu + ((u >> 16) & 1u);   // round-to-nearest-even
    return (bf16_t)(u >> 16);
}

// async global->LDS, 16B per lane
#define GLOAD_LDS16(g, l)                                                     \
    __builtin_amdgcn_global_load_lds(                                         \
        (const __attribute__((address_space(1))) void*)(g),                   \
        (__attribute__((address_space(3))) void*)(l), 16, 0, 0)

// raw barrier + counted waits (used by the pipe2_ln core)
#define SBAR() __builtin_amdgcn_s_barrier()
#define WAITV(n)                                                              \
    do {                                                                      \
        asm volatile("s_waitcnt vmcnt(" #n ")" ::: "memory");                 \
        __builtin_amdgcn_sched_barrier(0);                                    \
    } while (0)

// pipe2_ln fragment read: (row R, k-chunk quad) of a [256]x32 panel in
// pair-row-XOR-swizzled chunk order.
#define FRAG16(L, R)                                                          \
    (*(const short8*)&(L)[((((R) >> 1) * 8) +                                  \
        (((((R) & 1) << 2) | quad) ^ (((R) >> 1) & 7))) * 8])

// ---------------------------------------------------------------------------
// prep_all: ALL weight transposes + bias concat in ONE dispatch.
// Flat decode over 3108 blocks (tile math byte-identical to the proven
// conv_transpose_kernel).
// ---------------------------------------------------------------------------
__global__ __launch_bounds__(256) void prep_all(
    const float* __restrict__ Wq, const float* __restrict__ Wk,
    const float* __restrict__ Wv, const float* __restrict__ Wo,
    const float* __restrict__ W1, const float* __restrict__ W2,
    const float* __restrict__ embW,
    const float* __restrict__ bq, const float* __restrict__ bk,
    const float* __restrict__ bv,
    bf16_t* __restrict__ WqkvT, bf16_t* __restrict__ WoT,
    bf16_t* __restrict__ W1T, bf16_t* __restrict__ W2T,
    bf16_t* __restrict__ embWT, float* __restrict__ bqkv)
{
    const int id = blockIdx.x;
    if (id >= 3104) {                          // concat_bias: 4 blocks
        const int l = id - 3104, j = threadIdx.x;
        bqkv[l * 768 + j]       = bq[l * 256 + j];
        bqkv[l * 768 + 256 + j] = bk[l * 256 + j];
        bqkv[l * 768 + 512 + j] = bv[l * 256 + j];
        return;
    }
    const float* in; bf16_t* out;
    int R, C, z, x, y; size_t ils, ols;
    if (id < 1024) {
        const int seg = id >> 8;               // 0..3: Wq,Wk,Wv,Wo
        const int t = id & 255;
        z = t >> 6; const int tt = t & 63; x = tt & 7; y = tt >> 3;
        R = 256; C = 256; ils = 65536;
        if (seg == 0)      { in = Wq; out = WqkvT;              ols = 3 * 65536; }
        else if (seg == 1) { in = Wk; out = WqkvT + 65536;      ols = 3 * 65536; }
        else if (seg == 2) { in = Wv; out = WqkvT + 2 * 65536;  ols = 3 * 65536; }
        else               { in = Wo; out = WoT;                ols = 65536;     }
    } else if (id < 2048) {
        const int t2 = id - 1024; z = t2 >> 8; const int t = t2 & 255;
        x = t & 31; y = t >> 5; R = 256; C = 1024; ils = ols = 262144;
        in = W1; out = W1T;
    } else if (id < 3072) {
        const int t2 = id - 2048; z = t2 >> 8; const int t = t2 & 255;
        x = t & 7; y = t >> 3; R = 1024; C = 256; ils = ols = 262144;
        in = W2; out = W2T;
    } else {
        const int t = id - 3072; z = 0; x = t & 7; y = t >> 3;
        R = 128; C = 256; ils = 0; ols = 0;
        in = embW; out = embWT;
    }
    __shared__ float tile[32][33];
    const size_t ib = (size_t)z * ils;
    const size_t ob = (size_t)z * ols;
    const int r0 = y * 32, c0 = x * 32;
    const int tx = threadIdx.x & 31, ty = threadIdx.x >> 5;   // 32 x 8
#pragma unroll
    for (int rr = ty; rr < 32; rr += 8)
        tile[rr][tx] = in[ib + (size_t)(r0 + rr) * C + c0 + tx];
    __syncthreads();
#pragma unroll
    for (int rr = ty; rr < 32; rr += 8)
        out[ob + (size_t)(c0 + rr) * R + r0 + tx] = f2b(tile[tx][rr]);
}

// ---------------------------------------------------------------------------
// Embed A-prep: Ain[b*4096+l][128] = (l==0) ? 0 : bf16(ins[b][l-1][:])
// ---------------------------------------------------------------------------
__global__ __launch_bounds__(256) void prep_a_kernel(
    const float* __restrict__ ins, bf16_t* __restrict__ Ain)
{
    const int row = blockIdx.x * 2 + (threadIdx.x >> 7);
    const int j = threadIdx.x & 127;
    const int b = row >> 12, l = row & (LSEQ - 1);
    bf16_t v = 0;
    if (l != 0) v = f2b(ins[((size_t)b * 4095 + (l - 1)) * 128 + j]);
    Ain[(size_t)row * 128 + j] = v;
}

// X[b,0,:] = resets ? 0 : hidden
__global__ __launch_bounds__(256) void fix_row0_kernel(
    const float* __restrict__ hidden, const int* __restrict__ resets,
    bf16_t* __restrict__ X)
{
    const int b = blockIdx.x, j = threadIdx.x;
    float v = resets[b] ? 0.f : hidden[b * HIDD + j];
    X[((size_t)b * LSEQ) * HIDD + j] = f2b(v);
}

// ---------------------------------------------------------------------------
// MFMA GEMM (r14/r22/r24, proven fastest): C = act(A @ W + bias); WT[N][K].
// 512 thr = 8 waves, block 128x256, wave 64x64 (2m x 4n). XOR-swizzled LDS.
// Optional side-task: zero zbuf[0..zn) at entry (QKV instantiation zeroes KV).
// 1-D grid with XCD-aware decode. Requires M/128 % 8 == 0.
// ---------------------------------------------------------------------------
template <int MODE>
__global__ __launch_bounds__(512) void gemm_mfma(
    const bf16_t* __restrict__ A, const bf16_t* __restrict__ WT,
    const float* __restrict__ bias, bf16_t* __restrict__ C,
    int M, int N, int K, int lda, int ldc,
    float* __restrict__ zbuf, int zn)
{
    __shared__ __align__(16) bf16_t As[128 * 64];   // 16 KB
    __shared__ __align__(16) bf16_t Bs[256 * 64];   // 32 KB
    const int tid = threadIdx.x;
    const int wave = tid >> 6, lane = tid & 63;

    if (zbuf) {                                     // side-task: zero KV
        const int zi = blockIdx.x * 512 + tid;
        if (zi < zn) zbuf[zi] = 0.f;
    }

    // XCD-aware decode (identity when N==256)
    const int Nn = N >> 8;
    const int id = blockIdx.x;
    const int s = id >> 3;
    const int bm = ((id & 7) + ((s / Nn) << 3)) * 128;
    const int bn = (s % Nn) * 256;

    const int quad = lane >> 4, mr = lane & 15;
    const int mxor = mr & 7;
    const int wm0 = (wave & 1) * 64;       // m-half
    const int wn0 = (wave >> 1) * 64;      // n-quarter

    float4v acc[4][4];
#pragma unroll
    for (int i = 0; i < 4; i++)
#pragma unroll
        for (int j = 0; j < 4; j++) acc[i][j] = (float4v)(0.f);

    for (int k0 = 0; k0 < K; k0 += 64) {
#pragma unroll
        for (int it = 0; it < 2; it++) {            // A: 1024 chunks
            const int c = it * 512 + tid;
            const int r = c >> 3;
            const int kofs = ((c & 7) ^ (r & 7)) * 8;
            GLOAD_LDS16(A + (size_t)(bm + r) * lda + k0 + kofs, &As[c * 8]);
        }
#pragma unroll
        for (int it = 0; it < 4; it++) {            // B: 2048 chunks
            const int c = it * 512 + tid;
            const int r = c >> 3;
            const int kofs = ((c & 7) ^ (r & 7)) * 8;
            GLOAD_LDS16(WT + (size_t)(bn + r) * K + k0 + kofs, &Bs[c * 8]);
        }
        __syncthreads();
#pragma unroll
        for (int kk = 0; kk < 8; kk += 4) {
            short8 a[4], b[4];
#pragma unroll
            for (int i = 0; i < 4; i++)
                a[i] = *(const short8*)&As[((wm0 + i * 16 + mr) * 8 + ((quad + kk) ^ mxor)) * 8];
#pragma unroll
            for (int j = 0; j < 4; j++)
                b[j] = *(const short8*)&Bs[((wn0 + j * 16 + mr) * 8 + ((quad + kk) ^ mxor)) * 8];
#pragma unroll
            for (int i = 0; i < 4; i++)
#pragma unroll
                for (int j = 0; j < 4; j++)
                    acc[i][j] = __builtin_amdgcn_mfma_f32_16x16x32_bf16(
                        a[i], b[j], acc[i][j], 0, 0, 0);
        }
        __syncthreads();
    }

    float bcol[4];
#pragma unroll
    for (int j = 0; j < 4; j++) bcol[j] = bias[bn + wn0 + j * 16 + mr];
#pragma unroll
    for (int i = 0; i < 4; i++) {
#pragma unroll
        for (int r = 0; r < 4; r++) {
            const int grow = bm + wm0 + i * 16 + quad * 4 + r;
            bf16_t* crow = C + (size_t)grow * ldc + bn + wn0 + mr;
#pragma unroll
            for (int j = 0; j < 4; j++) {
                float v = acc[i][j][r] + bcol[j];
                if (MODE == 1) v = fmaxf(v, 0.f);
                crow[j * 16] = f2b(v);
            }
        }
    }
}

// ---------------------------------------------------------------------------
// Pipelined v2 core + fused LayerNorm epilogue (r19, proven for LN GEMMs):
// out = LN(2*(A@W + bias)) * sc + bi.  N=256 fixed, 256 rows/block.
// Used for Wo+LN1 (K=256) and FF2+LN2 (K=1024).
// ---------------------------------------------------------------------------
__global__ __launch_bounds__(512, 2) void gemm_pipe2_ln(
    const bf16_t* __restrict__ A, const bf16_t* __restrict__ WT,
    const float* __restrict__ bias, const float* __restrict__ sc,
    const float* __restrict__ bi, bf16_t* __restrict__ out,
    int K, int lda)
{
    __shared__ __align__(16) bf16_t As[3][256 * 32];   // 48 KB
    __shared__ __align__(16) bf16_t Bs[3][256 * 32];   // 48 KB
    __shared__ float red[8][128][2];                   // 8 KB
    __shared__ float fin[256][2];                      // 2 KB

    const int tid = threadIdx.x;
    const int wave = tid >> 6, lane = tid & 63;
    const int quad = lane >> 4, mr = lane & 15;
    const int bm = blockIdx.x << 8;                    // *256

    const int wm = (wave & 1) << 7;
    const int wn = (wave >> 1) << 6;

    const int KT = K >> 5;

    float bcol[4], scv[4], biv[4];
#pragma unroll
    for (int j = 0; j < 4; ++j) {
        bcol[j] = bias[wn + j * 16 + mr];
        scv[j]  = sc[wn + j * 16 + mr];
        biv[j]  = bi[wn + j * 16 + mr];
    }
    asm volatile("s_waitcnt vmcnt(0)" ::: "memory");
    __builtin_amdgcn_sched_barrier(0);

    auto stageA = [&](int t) {
        const int k0 = t << 5;
        bf16_t* L = &As[t % 3][0];
#pragma unroll
        for (int it = 0; it < 2; ++it) {
            const int c = it * 512 + tid;
            const int r = c >> 2;
            const int up = ((((r & 1) << 2) | (c & 3)) ^ ((r >> 1) & 7));
            const int grow = ((r >> 1) << 1) | (up >> 2);
            GLOAD_LDS16(A + (size_t)(bm + grow) * lda + k0 + ((up & 3) << 3),
                        L + c * 8);
        }
    };
    auto stageB = [&](int t) {
        const int k0 = t << 5;
        bf16_t* L = &Bs[t % 3][0];
#pragma unroll
        for (int it = 0; it < 2; ++it) {
            const int c = it * 512 + tid;
            const int r = c >> 2;
            const int up = ((((r & 1) << 2) | (c & 3)) ^ ((r >> 1) & 7));
            const int grow = ((r >> 1) << 1) | (up >> 2);
            GLOAD_LDS16(WT + (size_t)grow * K + k0 + ((up & 3) << 3),
                        L + c * 8);
        }
    };

    float4v acc[8][4];
#pragma unroll
    for (int i = 0; i < 8; i++)
#pragma unroll
        for (int j = 0; j < 4; j++) acc[i][j] = (float4v)(0.f);

    const int P = KT < 2 ? KT : 2;
    for (int tt = 0; tt < P; ++tt) { stageA(tt); stageB(tt); }

    for (int t = 0; t < KT; ++t) {
        if (t < KT - 1) { WAITV(4); } else { WAITV(0); }
        SBAR();
        __builtin_amdgcn_sched_barrier(0);
        const bf16_t* LA = &As[t % 3][0];
        const bf16_t* LB = &Bs[t % 3][0];
        short8 a0[4], a1[4], b[4];
#pragma unroll
        for (int j = 0; j < 4; ++j) b[j]  = FRAG16(LB, wn + j * 16 + mr);
#pragma unroll
        for (int i = 0; i < 4; ++i) a0[i] = FRAG16(LA, wm + i * 16 + mr);
#pragma unroll
        for (int i = 0; i < 4; ++i) a1[i] = FRAG16(LA, wm + 64 + i * 16 + mr);
        if (t + 2 < KT) { stageA(t + 2); stageB(t + 2); }
        __builtin_amdgcn_s_setprio(1);
        __builtin_amdgcn_sched_barrier(0);
#pragma unroll
        for (int i = 0; i < 4; ++i)
#pragma unroll
            for (int j = 0; j < 4; ++j)
                acc[i][j] = __builtin_amdgcn_mfma_f32_16x16x32_bf16(
                    a0[i], b[j], acc[i][j], 0, 0, 0);
#pragma unroll
        for (int i = 0; i < 4; ++i)
#pragma unroll
            for (int j = 0; j < 4; ++j)
                acc[4 + i][j] = __builtin_amdgcn_mfma_f32_16x16x32_bf16(
                    a1[i], b[j], acc[4 + i][j], 0, 0, 0);
        __builtin_amdgcn_sched_barrier(0);
        __builtin_amdgcn_s_setprio(0);
    }

#pragma unroll
    for (int i = 0; i < 8; ++i) {
#pragma unroll
        for (int r = 0; r < 4; ++r) {
            float ss = 0.f, s2 = 0.f;
#pragma unroll
            for (int j = 0; j < 4; ++j) {
                const float v = 2.0f * (acc[i][j][r] + bcol[j]);
                ss += v; s2 += v * v;
            }
#pragma unroll
            for (int off = 1; off < 16; off <<= 1) {
                ss += __shfl_xor(ss, off, 64);
                s2 += __shfl_xor(s2, off, 64);
            }
            if (mr == 0) {
                const int rl = i * 16 + quad * 4 + r;
                red[wave][rl][0] = ss;
                red[wave][rl][1] = s2;
            }
        }
    }
    __syncthreads();
    {
        const int R = tid >> 1, p = tid & 1;
        const int mh = R >> 7, rl = R & 127;
        fin[R][p] = red[mh][rl][p] + red[mh + 2][rl][p]
                  + red[mh + 4][rl][p] + red[mh + 6][rl][p];
    }
    __syncthreads();

#pragma unroll
    for (int i = 0; i < 8; ++i) {
#pragma unroll
        for (int r = 0; r < 4; ++r) {
            const int R = wm + i * 16 + quad * 4 + r;
            const float mean = fin[R][0] * (1.0f / 256.0f);
            const float var  = fin[R][1] * (1.0f / 256.0f) - mean * mean;
            const float rs = rsqrtf(var + LNEPS_F);
            bf16_t* crow = out + (size_t)(bm + R) * 256 + wn + mr;
#pragma unroll
            for (int j = 0; j < 4; ++j) {
                const float v = 2.0f * (acc[i][j][r] + bcol[j]);
                crow[j * 16] = f2b((v - mean) * rs * scv[j] + biv[j]);
            }
        }
    }
}

// ---------------------------------------------------------------------------
// FAVOR A-gen (standalone, proven): Afav = (qp @ kv) / (qp @ kps).
// ---------------------------------------------------------------------------
__global__ __launch_bounds__(512) void favor_a_kernel(
    const bf16_t* __restrict__ QKV, const float* __restrict__ KV,
    bf16_t* __restrict__ Afav)
{
    __shared__ __align__(16) bf16_t kvT[NHEAD * 34 * 36];   // 19.1 KB

    const int tid = threadIdx.x;
    const int wave = tid >> 6, lane = tid & 63;
    const int bm = blockIdx.x * 128;
    const int b = bm >> 12;
    const int quad = lane >> 4, mr = lane & 15;

    for (int e = tid; e < NHEAD * 34 * 32; e += 512) {
        const int h = e / (34 * 32);
        const int rem = e - h * (34 * 32);
        const int d = rem >> 5, m = rem & 31;
        bf16_t v = 0;
        if (d < 33) v = f2b(KV[((size_t)(b * NHEAD + h)) * (32 * 33) + m * 33 + d]);
        kvT[(h * 34 + d) * 36 + m] = v;
    }
    __syncthreads();

    const int Rrow = bm + wave * 16 + mr;
    const size_t abase = (size_t)(bm + wave * 16) * 256;

    short8 araw[NHEAD];
#pragma unroll
    for (int h = 0; h < NHEAD; ++h)
        araw[h] = *(const short8*)(QKV + (size_t)Rrow * 768 + h * 32 + quad * 8);

#pragma unroll
    for (int h = 0; h < NHEAD; ++h) {
        short8 a;
#pragma unroll
        for (int j = 0; j < 8; j++)
            a[j] = (short)f2b(fmaxf(b2f((bf16_t)araw[h][j]), 0.f) + KEPS_F);
        short8 bf0 = *(const short8*)&kvT[(h * 34 + mr) * 36 + quad * 8];
        short8 bf1 = *(const short8*)&kvT[(h * 34 + 16 + mr) * 36 + quad * 8];
        short8 bden;
#pragma unroll
        for (int j = 0; j < 8; j++) bden[j] = 0;
        if (mr == 0)
            bden = *(const short8*)&kvT[(h * 34 + 32) * 36 + quad * 8];
        float4v c0 = __builtin_amdgcn_mfma_f32_16x16x32_bf16(a, bf0, (float4v)(0.f), 0, 0, 0);
        float4v c1 = __builtin_amdgcn_mfma_f32_16x16x32_bf16(a, bf1, (float4v)(0.f), 0, 0, 0);
        float4v c2 = __builtin_amdgcn_mfma_f32_16x16x32_bf16(a, bden, (float4v)(0.f), 0, 0, 0);
#pragma unroll
        for (int r = 0; r < 4; r++) {
            const float den = __shfl(c2[r], quad << 4);
            const float rinv = 1.0f / den;
            const int rl = quad * 4 + r;
            Afav[abase + (size_t)rl * 256 + h * 32 + mr]      = f2b(c0[r] * rinv);
            Afav[abase + (size_t)rl * 256 + h * 32 + 16 + mr] = f2b(c1[r] * rinv);
        }
    }
}

// ---------------------------------------------------------------------------
// FAVOR kv state via MFMA. Per (b,h): KV[32x33] = kp^T[32xL] @ [V|1][Lx33].
// (KV is zeroed by the QKV GEMM's entry side-task.)  Proven r24 version.
// ---------------------------------------------------------------------------
__global__ __launch_bounds__(256) void kv_mfma(
    const bf16_t* __restrict__ QKV, float* __restrict__ KV)
{
    __shared__ __align__(16) char smem[24576];
    bf16_t (*kp)[36] = (bf16_t(*)[36])smem;                 // 128x36x2 = 9216 B
    bf16_t (*vv)[52] = (bf16_t(*)[52])(smem + 9216);        // 128x52x2 = 13312 B
    float (*red)[6][64][4] = (float(*)[6][64][4])smem;      // 24576 B (aliases)

    const int bh = blockIdx.x;
    const int b = bh >> 3, h = bh & 7;
    const size_t rowbase = (size_t)b * LSEQ + blockIdx.y * 512;
    const int tid = threadIdx.x;
    const int wave = tid >> 6, lane = tid & 63;
    const int quad = lane >> 4, mr = lane & 15;

    for (int e = tid; e < 128 * 20; e += 256) {
        const int l = e / 20, c = 32 + (e % 20);
        vv[l][c] = (c == 32) ? (bf16_t)0x3F80 : (bf16_t)0;
    }

    float4v acc[2][3];
#pragma unroll
    for (int i = 0; i < 2; i++)
#pragma unroll
        for (int t = 0; t < 3; t++) acc[i][t] = (float4v)(0.f);

    for (int pass = 0; pass < 4; pass++) {
        __syncthreads();
        const size_t lp = rowbase + pass * 128;
#pragma unroll
        for (int it = 0; it < 4; it++) {
            const int e = tid + it * 256;
            const int l = e >> 3, c0 = (e & 7) * 4;
            const bf16_t* src = QKV + (lp + l) * 768 + 256 + h * 32 + c0;
            ushort4 kq = *(const ushort4*)src;
            ushort4 vq = *(const ushort4*)(src + 256);
            ushort4 ko;
            ko.x = f2b(fmaxf(b2f(kq.x), 0.f) + KEPS_F);
            ko.y = f2b(fmaxf(b2f(kq.y), 0.f) + KEPS_F);
            ko.z = f2b(fmaxf(b2f(kq.z), 0.f) + KEPS_F);
            ko.w = f2b(fmaxf(b2f(kq.w), 0.f) + KEPS_F);
            *(ushort4*)&kp[l][c0] = ko;
            *(ushort4*)&vv[l][c0] = vq;
        }
        __syncthreads();

        const int lw = wave * 32 + quad * 8;
        short8 a[2], bb[3];
#pragma unroll
        for (int i = 0; i < 2; i++)
#pragma unroll
            for (int j = 0; j < 8; j++)
                a[i][j] = (short)kp[lw + j][i * 16 + mr];
#pragma unroll
        for (int t = 0; t < 3; t++)
#pragma unroll
            for (int j = 0; j < 8; j++)
                bb[t][j] = (short)vv[lw + j][t * 16 + mr];
#pragma unroll
        for (int i = 0; i < 2; i++)
#pragma unroll
            for (int t = 0; t < 3; t++)
                acc[i][t] = __builtin_amdgcn_mfma_f32_16x16x32_bf16(
                    a[i], bb[t], acc[i][t], 0, 0, 0);
    }

    __syncthreads();
#pragma unroll
    for (int i = 0; i < 2; i++)
#pragma unroll
        for (int t = 0; t < 3; t++)
#pragma unroll
            for (int r = 0; r < 4; r++)
                red[wave][i * 3 + t][lane][r] = acc[i][t][r];
    __syncthreads();

    float* dst = KV + (size_t)bh * (32 * 33);
    for (int e = tid; e < 6 * 64 * 4; e += 256) {
        const int t = e >> 8, li = (e >> 2) & 63, r = e & 3;
        const float s = red[0][t][li][r] + red[1][t][li][r]
                      + red[2][t][li][r] + red[3][t][li][r];
        const int i = t / 3, j = t % 3;
        const int m = i * 16 + (li >> 4) * 4 + r;
        const int d = j * 16 + (li & 15);
        if (d < 33) atomicAdd(&dst[m * 33 + d], s);
    }
}

// ---------------------------------------------------------------------------
// Head (fp32 out): out[0:4096] = x[:,0,:] ; out[4096:4608] = x@qpW + qpb
// ---------------------------------------------------------------------------
__global__ __launch_bounds__(256) void head_kernel(
    const bf16_t* __restrict__ X, const float* __restrict__ qpW,
    const float* __restrict__ qpb, float* __restrict__ out)
{
    const int b = blockIdx.x, j = threadIdx.x;
    __shared__ float xr[HIDD];
    float v = b2f(X[((size_t)b * LSEQ) * HIDD + j]);
    xr[j] = v;
    out[b * HIDD + j] = v;
    __syncthreads();
    if (j < 32) {
        float acc = qpb[j];
        for (int d = 0; d < HIDD; d++)
            acc = fmaf(xr[d], qpW[d * 32 + j], acc);
        out[NB * HIDD + b * 32 + j] = acc;
    }
}

// ---------------------------------------------------------------------------
extern "C" void kernel_launch(void* const* d_in, const int* in_sizes, int n_in,
                              void* d_out, int out_size, void* d_ws, size_t ws_size,
                              hipStream_t stream)
{
    const float* hidden = (const float*)d_in[0];
    const float* ins    = (const float*)d_in[1];
    const int*   resets = (const int*)d_in[2];
    const float* embW   = (const float*)d_in[3];
    const float* embb   = (const float*)d_in[4];
    const float* Wq = (const float*)d_in[5];
    const float* bq = (const float*)d_in[6];
    const float* Wk = (const float*)d_in[7];
    const float* bk = (const float*)d_in[8];
    const float* Wv = (const float*)d_in[9];
    const float* bv = (const float*)d_in[10];
    const float* Wo = (const float*)d_in[11];
    const float* bo = (const float*)d_in[12];
    const float* ln1s = (const float*)d_in[13];
    const float* ln1b = (const float*)d_in[14];
    const float* W1 = (const float*)d_in[15];
    const float* b1 = (const float*)d_in[16];
    const float* W2 = (const float*)d_in[17];
    const float* b2 = (const float*)d_in[18];
    const float* ln2s = (const float*)d_in[19];
    const float* ln2b = (const float*)d_in[20];
    const float* qpW = (const float*)d_in[21];
    const float* qpb = (const float*)d_in[22];

    // ---- workspace (~195 MB < 256 MiB) ----
    const size_t ACT_SZ = (size_t)MROWS * HIDD;            // 16.78M elems
    bf16_t* X    = (bf16_t*)d_ws;                          // 33.5 MB
    bf16_t* QKV  = X + ACT_SZ;                             // 65536x768 = 100.7 MB
    bf16_t* H1   = QKV;                                    // alias: 65536x1024 (134 MB span)
    bf16_t* Ain  = QKV;                                    // alias (pre-layer only)
    bf16_t* Afav = QKV + (size_t)MROWS * 768;              // spare tail of H1 span, 33.5 MB
    float*  KV   = (float*)(QKV + (size_t)MROWS * FFD);    // after H1 span
    float*  bqkv = KV + KV_ELEMS;                          // 4x768 f32
    bf16_t* WqkvT = (bf16_t*)(bqkv + NLAY * 768);          // [l][768][256]
    bf16_t* WoT   = WqkvT + (size_t)NLAY * 3 * HIDD * HIDD;
    bf16_t* W1T   = WoT + (size_t)NLAY * HIDD * HIDD;
    bf16_t* W2T   = W1T + (size_t)NLAY * HIDD * FFD;
    bf16_t* embWT = W2T + (size_t)NLAY * FFD * HIDD;

    const dim3 blk(256);
    const dim3 blk512(512);
    const size_t HH = (size_t)HIDD * HIDD;

    // ALL weight prep in one dispatch
    prep_all<<<dim3(3108), blk, 0, stream>>>(
        Wq, Wk, Wv, Wo, W1, W2, embW, bq, bk, bv,
        WqkvT, WoT, W1T, W2T, embWT, bqkv);

    prep_a_kernel<<<MROWS / 2, blk, 0, stream>>>(ins, Ain);
    // embed: M=65536, N=256, K=128 -> 512 blocks (Nn=1)
    gemm_mfma<0><<<dim3(512), blk512, 0, stream>>>(Ain, embWT, embb, X, MROWS, HIDD, 128, 128, HIDD,
                                                   nullptr, 0);
    fix_row0_kernel<<<NB, blk, 0, stream>>>(hidden, resets, X);

    for (int l = 0; l < NLAY; l++) {
        // fused QKV projection (+ KV zero side-task):
        // X[M][256] @ Wqkv[256][768] -> QKV[M][768]
        gemm_mfma<0><<<dim3(512 * 3), blk512, 0, stream>>>(X, WqkvT + (size_t)l * 3 * HH,
                                                           bqkv + l * 768, QKV, MROWS, 768, HIDD, HIDD, 768,
                                                           KV, KV_ELEMS);

        kv_mfma<<<dim3(NB * NHEAD, 8), blk, 0, stream>>>(QKV, KV);

        // favor A-gen -> Afav (standalone, latency-tolerant)
        favor_a_kernel<<<dim3(MROWS / 128), blk512, 0, stream>>>(QKV, KV, Afav);

        // Wo + residual-doubling + LN1 via pipelined GEMM v2 (K=256) -> X
        gemm_pipe2_ln<<<dim3(256), blk512, 0, stream>>>(
            Afav, WoT + (size_t)l * HH, bo + l * HIDD,
            ln1s + l * HIDD, ln1b + l * HIDD, X, HIDD, HIDD);

        // FF1 (r14 core): X @ W1 -> H1 (over dead QKV region + spare)
        gemm_mfma<1><<<dim3(512 * 4), blk512, 0, stream>>>(X, W1T + (size_t)l * HIDD * FFD,
                                                           b1 + l * FFD, H1, MROWS, FFD, HIDD, HIDD, FFD,
                                                           nullptr, 0);
        // FF2 + residual-doubling + LN2 fused -> X (pipelined v2, K=1024)
        gemm_pipe2_ln<<<dim3(256), blk512, 0, stream>>>(
            H1, W2T + (size_t)l * FFD * HIDD, b2 + l * HIDD,
            ln2s + l * HIDD, ln2b + l * HIDD, X, FFD, FFD);
    }

    head_kernel<<<NB, blk, 0, stream>>>(X, qpW, qpb, (float*)d_out);
}